// Round 1
// baseline (351.206 us; speedup 1.0000x reference)
//
#include <hip/hip_runtime.h>
#include <stdint.h>

#define N_ROWS 4096
#define DDIM   1024
#define M_TOT  8192

typedef __attribute__((ext_vector_type(8))) short bf16x8;
typedef __attribute__((ext_vector_type(4))) float f32x4;

__device__ __forceinline__ unsigned short f2bf(float x) {
  union { float f; uint32_t u; } v; v.f = x;
  uint32_t r = v.u + 0x7FFFu + ((v.u >> 16) & 1u);
  return (unsigned short)(r >> 16);
}

__device__ __forceinline__ void gload_lds16(const void* g, void* l) {
  __builtin_amdgcn_global_load_lds(
      (const __attribute__((address_space(1))) uint32_t*)g,
      (__attribute__((address_space(3))) uint32_t*)l, 16, 0, 0);
}

// ---------- kernel 1: row-normalize both inputs, emit bf16 z, pos/align sums ----------
__global__ __launch_bounds__(256) void knorm(const float* __restrict__ p1,
                                             const float* __restrict__ p2,
                                             unsigned short* __restrict__ z,
                                             float* __restrict__ scal) {
  const int r = blockIdx.x;
  const int t = threadIdx.x;
  const int lane = t & 63, w = t >> 6;
  __shared__ float red0[4], red1[4];

  const float4 a = ((const float4*)(p1 + (size_t)r * DDIM))[t];
  const float4 b = ((const float4*)(p2 + (size_t)r * DDIM))[t];
  float s1 = a.x*a.x + a.y*a.y + a.z*a.z + a.w*a.w;
  float s2 = b.x*b.x + b.y*b.y + b.z*b.z + b.w*b.w;
  for (int off = 1; off < 64; off <<= 1) { s1 += __shfl_xor(s1, off); s2 += __shfl_xor(s2, off); }
  if (lane == 0) { red0[w] = s1; red1[w] = s2; }
  __syncthreads();
  const float S1 = red0[0] + red0[1] + red0[2] + red0[3];
  const float S2 = red1[0] + red1[1] + red1[2] + red1[3];
  const float r1 = 1.0f / sqrtf(S1);
  const float r2 = 1.0f / sqrtf(S2);
  const float n1x = a.x*r1, n1y = a.y*r1, n1z = a.z*r1, n1w = a.w*r1;
  const float n2x = b.x*r2, n2y = b.y*r2, n2z = b.z*r2, n2w = b.w*r2;
  float pos = n1x*n2x + n1y*n2y + n1z*n2z + n1w*n2w;
  float al  = (n1x-n2x)*(n1x-n2x) + (n1y-n2y)*(n1y-n2y)
            + (n1z-n2z)*(n1z-n2z) + (n1w-n2w)*(n1w-n2w);
  __syncthreads();
  for (int off = 1; off < 64; off <<= 1) { pos += __shfl_xor(pos, off); al += __shfl_xor(al, off); }
  if (lane == 0) { red0[w] = pos; red1[w] = al; }
  __syncthreads();
  if (t == 0) {
    atomicAdd(&scal[0], red0[0] + red0[1] + red0[2] + red0[3]);
    atomicAdd(&scal[1], red1[0] + red1[1] + red1[2] + red1[3]);
  }
  ushort4 o1, o2;
  o1.x = f2bf(n1x); o1.y = f2bf(n1y); o1.z = f2bf(n1z); o1.w = f2bf(n1w);
  o2.x = f2bf(n2x); o2.y = f2bf(n2y); o2.z = f2bf(n2z); o2.w = f2bf(n2w);
  ((ushort4*)(z + (size_t)r * DDIM))[t] = o1;
  ((ushort4*)(z + (size_t)(r + N_ROWS) * DDIM))[t] = o2;
}

// ---------- kernel 2: fused z@z^T with exp row-sums + uniformity sums ----------
// 128x128 tile, BK=64, 4 waves (2x2), each wave 64x64 via 4x4 16x16x32 MFMA frags.
// LDS rows are 128B; XOR swizzle byte^=((row&7)<<4) applied on the global SOURCE
// address (linear global_load_lds dest) and on the ds_read addresses (rule #21).
__global__ __launch_bounds__(256) void kgemm(const unsigned short* __restrict__ z,
                                             float* __restrict__ denom,
                                             float* __restrict__ scal) {
  __shared__ unsigned short As[128 * 64];
  __shared__ unsigned short Bs[128 * 64];
  __shared__ float red[4];

  const int tid  = threadIdx.x;
  const int lane = tid & 63;
  const int w    = tid >> 6;
  const int wr   = w >> 1, wc = w & 1;
  const int tx = blockIdx.x, ty = blockIdx.y;
  const int row0 = ty * 128, col0 = tx * 128;

  const int l8  = lane & 7;        // 16B chunk within a 128B LDS row
  const int ld8 = lane >> 3;       // row within the 8-row group of one gload
  const int swz = ((l8 ^ ld8) << 4);

  const int lr = lane >> 4;        // k-group (inputs) / row-group (acc)
  const int lc = lane & 15;        // frag row (A) / col (B, C/D)

  f32x4 acc[4][4] = {};
  const char* zb = (const char*)z;

  for (int kt = 0; kt < DDIM / 64; ++kt) {
    const int kbyte = kt * 128;
#pragma unroll
    for (int t4 = 0; t4 < 4; ++t4) {
      const int rr = w * 32 + t4 * 8 + ld8;           // tile row 0..127
      const char* gA = zb + ((size_t)(row0 + rr) * (DDIM * 2)) + kbyte + swz;
      const char* gB = zb + ((size_t)(col0 + rr) * (DDIM * 2)) + kbyte + swz;
      gload_lds16(gA, (char*)As + rr * 128 + l8 * 16);
      gload_lds16(gB, (char*)Bs + rr * 128 + l8 * 16);
    }
    __syncthreads();
#pragma unroll
    for (int kk = 0; kk < 2; ++kk) {
      bf16x8 af[4], bfr[4];
#pragma unroll
      for (int m = 0; m < 4; ++m) {
        const int r = wr * 64 + m * 16 + lc;
        af[m] = *(const bf16x8*)((const char*)As + r * 128
                 + ((kk * 64 + lr * 16) ^ ((r & 7) << 4)));
      }
#pragma unroll
      for (int n = 0; n < 4; ++n) {
        const int c = wc * 64 + n * 16 + lc;
        bfr[n] = *(const bf16x8*)((const char*)Bs + c * 128
                 + ((kk * 64 + lr * 16) ^ ((c & 7) << 4)));
      }
#pragma unroll
      for (int m = 0; m < 4; ++m)
#pragma unroll
        for (int n = 0; n < 4; ++n)
          acc[m][n] = __builtin_amdgcn_mfma_f32_16x16x32_bf16(af[m], bfr[n], acc[m][n], 0, 0, 0);
    }
    __syncthreads();
  }

  // ---- fused epilogue ----
  const float RK10 = 14.426950408889634f;  // 10 * log2(e)
  const float K4   = 5.770780163555856f;   // 4 * log2(e)
  const bool diagWave = (tx == ty) && (wr == wc);
  const bool unif0 = (tx < 16) && (ty < 16);
  const bool unif1 = (tx >= 16) && (tx < 32) && (ty >= 16) && (ty < 32);
  const bool unif  = unif0 || unif1;
  float u = 0.0f;

#pragma unroll
  for (int m = 0; m < 4; ++m) {
#pragma unroll
    for (int i = 0; i < 4; ++i) {
      float rs = 0.0f;
#pragma unroll
      for (int n = 0; n < 4; ++n) {
        const float s = acc[m][n][i];
        const bool isdiag = diagWave && (m == n) && ((lr * 4 + i) == lc);
        float e = exp2f(s * RK10);
        if (isdiag) e = 0.0f;
        rs += e;
        if (unif) {
          float eu = exp2f(s * K4 - K4);
          if (isdiag) eu = 0.0f;
          u += eu;
        }
      }
      // reduce over the 16 columns held by lanes sharing lr (xor over low 4 bits)
      rs += __shfl_xor(rs, 1); rs += __shfl_xor(rs, 2);
      rs += __shfl_xor(rs, 4); rs += __shfl_xor(rs, 8);
      if (lc == 0) atomicAdd(&denom[row0 + wr * 64 + m * 16 + lr * 4 + i], rs);
    }
  }
  if (unif) {
    for (int off = 1; off < 64; off <<= 1) u += __shfl_xor(u, off);
    if (lane == 0) red[w] = u;
    __syncthreads();
    if (tid == 0) atomicAdd(&scal[unif0 ? 2 : 3], red[0] + red[1] + red[2] + red[3]);
  }
}

// ---------- kernel 3: sum of log(denom) ----------
__global__ __launch_bounds__(256) void klog(const float* __restrict__ denom,
                                            float* __restrict__ scal) {
  const int idx = blockIdx.x * 256 + threadIdx.x;
  const int lane = threadIdx.x & 63, w = threadIdx.x >> 6;
  __shared__ float red[4];
  float ld = logf(denom[idx]);
  for (int off = 1; off < 64; off <<= 1) ld += __shfl_xor(ld, off);
  if (lane == 0) red[w] = ld;
  __syncthreads();
  if (threadIdx.x == 0) atomicAdd(&scal[4], red[0] + red[1] + red[2] + red[3]);
}

// ---------- kernel 4: combine scalars ----------
__global__ void kfinal(const float* __restrict__ scal, float* __restrict__ out) {
  const float sum_pos = scal[0], sum_align = scal[1];
  const float U0 = scal[2], U1 = scal[3], sum_logd = scal[4];
  out[0] = (sum_logd - 20.0f * sum_pos) / 8192.0f;    // loss: (sum log d - 2*sum_pos/t)/2n
  out[1] = sum_align / 4096.0f;                        // lalign
  const float P = 2048.0f * 2047.0f * 0.5f;            // n_pairs per half
  out[2] = 0.5f * (logf(U0 * 0.5f / P) + logf(U1 * 0.5f / P));  // lunif
}

extern "C" void kernel_launch(void* const* d_in, const int* in_sizes, int n_in,
                              void* d_out, int out_size, void* d_ws, size_t ws_size,
                              hipStream_t stream) {
  const float* p1 = (const float*)d_in[0];
  const float* p2 = (const float*)d_in[1];
  float* out = (float*)d_out;
  char* ws = (char*)d_ws;
  unsigned short* z = (unsigned short*)ws;                    // 8192 x 1024 bf16 = 16 MB
  float* denom = (float*)(ws + (size_t)M_TOT * DDIM * 2);     // 8192 f32
  float* scal  = denom + M_TOT;                               // [pos, align, U0, U1, logd]

  hipMemsetAsync(denom, 0, (M_TOT + 8) * sizeof(float), stream);
  knorm<<<N_ROWS, 256, 0, stream>>>(p1, p2, z, scal);
  dim3 g(64, 64);
  kgemm<<<g, 256, 0, stream>>>(z, denom, scal);
  klog<<<M_TOT / 256, 256, 0, stream>>>(denom, scal);
  kfinal<<<1, 1, 0, stream>>>(scal, out);
}

// Round 2
// 250.240 us; speedup vs baseline: 1.4035x; 1.4035x over previous
//
#include <hip/hip_runtime.h>
#include <stdint.h>

#define N_ROWS 4096
#define DDIM   1024
#define M_TOT  8192

typedef __attribute__((ext_vector_type(8))) short bf16x8;
typedef __attribute__((ext_vector_type(4))) float f32x4;

__device__ __forceinline__ unsigned short f2bf(float x) {
  union { float f; uint32_t u; } v; v.f = x;
  uint32_t r = v.u + 0x7FFFu + ((v.u >> 16) & 1u);
  return (unsigned short)(r >> 16);
}

__device__ __forceinline__ void gload_lds16(const void* g, void* l) {
  __builtin_amdgcn_global_load_lds(
      (const __attribute__((address_space(1))) uint32_t*)g,
      (__attribute__((address_space(3))) uint32_t*)l, 16, 0, 0);
}

// ---------- kernel 1: row-normalize both inputs, emit bf16 z, pos/align sums ----------
__global__ __launch_bounds__(256) void knorm(const float* __restrict__ p1,
                                             const float* __restrict__ p2,
                                             unsigned short* __restrict__ z,
                                             float* __restrict__ scal) {
  const int r = blockIdx.x;
  const int t = threadIdx.x;
  const int lane = t & 63, w = t >> 6;
  __shared__ float red0[4], red1[4];

  const float4 a = ((const float4*)(p1 + (size_t)r * DDIM))[t];
  const float4 b = ((const float4*)(p2 + (size_t)r * DDIM))[t];
  float s1 = a.x*a.x + a.y*a.y + a.z*a.z + a.w*a.w;
  float s2 = b.x*b.x + b.y*b.y + b.z*b.z + b.w*b.w;
  for (int off = 1; off < 64; off <<= 1) { s1 += __shfl_xor(s1, off); s2 += __shfl_xor(s2, off); }
  if (lane == 0) { red0[w] = s1; red1[w] = s2; }
  __syncthreads();
  const float S1 = red0[0] + red0[1] + red0[2] + red0[3];
  const float S2 = red1[0] + red1[1] + red1[2] + red1[3];
  const float r1 = 1.0f / sqrtf(S1);
  const float r2 = 1.0f / sqrtf(S2);
  const float n1x = a.x*r1, n1y = a.y*r1, n1z = a.z*r1, n1w = a.w*r1;
  const float n2x = b.x*r2, n2y = b.y*r2, n2z = b.z*r2, n2w = b.w*r2;
  float pos = n1x*n2x + n1y*n2y + n1z*n2z + n1w*n2w;
  float al  = (n1x-n2x)*(n1x-n2x) + (n1y-n2y)*(n1y-n2y)
            + (n1z-n2z)*(n1z-n2z) + (n1w-n2w)*(n1w-n2w);
  __syncthreads();
  for (int off = 1; off < 64; off <<= 1) { pos += __shfl_xor(pos, off); al += __shfl_xor(al, off); }
  if (lane == 0) { red0[w] = pos; red1[w] = al; }
  __syncthreads();
  if (t == 0) {
    atomicAdd(&scal[0], red0[0] + red0[1] + red0[2] + red0[3]);
    atomicAdd(&scal[1], red1[0] + red1[1] + red1[2] + red1[3]);
  }
  ushort4 o1, o2;
  o1.x = f2bf(n1x); o1.y = f2bf(n1y); o1.z = f2bf(n1z); o1.w = f2bf(n1w);
  o2.x = f2bf(n2x); o2.y = f2bf(n2y); o2.z = f2bf(n2z); o2.w = f2bf(n2w);
  ((ushort4*)(z + (size_t)r * DDIM))[t] = o1;
  ((ushort4*)(z + (size_t)(r + N_ROWS) * DDIM))[t] = o2;
}

// ---------- kernel 2: fused z@z^T, LOWER-TRIANGLE tiles only ----------
// 128x128 tile, BK=64, 4 waves (2x2), each wave 64x64 via 4x4 16x16x32 MFMA frags.
// Off-diagonal tiles (tx<ty): row-sums -> denom[block ty], col-sums -> denom[block tx]
// (symmetry: column-sum == mirrored row-sum, bitwise identical). Diagonal tiles:
// full tile, row-sums only, exclude the true diagonal.
__global__ __launch_bounds__(256) void kgemm(const unsigned short* __restrict__ z,
                                             float* __restrict__ denom,
                                             float* __restrict__ scal) {
  __shared__ unsigned short As[128 * 64];
  __shared__ unsigned short Bs[128 * 64];
  __shared__ float red[4];

  const int tid  = threadIdx.x;
  const int lane = tid & 63;
  const int w    = tid >> 6;
  const int wr   = w >> 1, wc = w & 1;

  // decode lower-triangle tile index: k -> (ty, tx), tx <= ty
  int k = blockIdx.x;
  int ty = (int)((sqrtf(8.0f * (float)k + 1.0f) - 1.0f) * 0.5f);
  while ((ty + 1) * (ty + 2) / 2 <= k) ++ty;
  while (ty * (ty + 1) / 2 > k) --ty;
  const int tx = k - ty * (ty + 1) / 2;

  const int row0 = ty * 128, col0 = tx * 128;
  const bool offdiag = (tx != ty);

  const int l8  = lane & 7;        // 16B chunk within a 128B LDS row
  const int ld8 = lane >> 3;       // row within the 8-row group of one gload
  const int swz = ((l8 ^ ld8) << 4);

  const int lr = lane >> 4;        // k-group (inputs) / row-group (acc)
  const int lc = lane & 15;        // frag row (A) / col (B, C/D)

  f32x4 acc[4][4] = {};
  const char* zb = (const char*)z;

  for (int kt = 0; kt < DDIM / 64; ++kt) {
    const int kbyte = kt * 128;
#pragma unroll
    for (int t4 = 0; t4 < 4; ++t4) {
      const int rr = w * 32 + t4 * 8 + ld8;           // tile row 0..127
      const char* gA = zb + ((size_t)(row0 + rr) * (DDIM * 2)) + kbyte + swz;
      const char* gB = zb + ((size_t)(col0 + rr) * (DDIM * 2)) + kbyte + swz;
      gload_lds16(gA, (char*)As + rr * 128 + l8 * 16);
      gload_lds16(gB, (char*)Bs + rr * 128 + l8 * 16);
    }
    __syncthreads();
#pragma unroll
    for (int kk = 0; kk < 2; ++kk) {
      bf16x8 af[4], bfr[4];
#pragma unroll
      for (int m = 0; m < 4; ++m) {
        const int r = wr * 64 + m * 16 + lc;
        af[m] = *(const bf16x8*)((const char*)As + r * 128
                 + ((kk * 64 + lr * 16) ^ ((r & 7) << 4)));
      }
#pragma unroll
      for (int n = 0; n < 4; ++n) {
        const int c = wc * 64 + n * 16 + lc;
        bfr[n] = *(const bf16x8*)((const char*)Bs + c * 128
                 + ((kk * 64 + lr * 16) ^ ((c & 7) << 4)));
      }
#pragma unroll
      for (int m = 0; m < 4; ++m)
#pragma unroll
        for (int n = 0; n < 4; ++n)
          acc[m][n] = __builtin_amdgcn_mfma_f32_16x16x32_bf16(af[m], bfr[n], acc[m][n], 0, 0, 0);
    }
    __syncthreads();
  }

  // ---- fused epilogue ----
  const float RK10 = 14.426950408889634f;  // 10 * log2(e)
  const float K4   = 5.770780163555856f;   // 4 * log2(e)
  const bool diagWave = (!offdiag) && (wr == wc);
  const bool unif0 = (ty < 16);                          // both halves in [0,2048)
  const bool unif1 = (ty >= 16) && (ty < 32) && (tx >= 16);
  const bool unif  = unif0 || unif1;
  float u = 0.0f;
  float cs[4] = {0.0f, 0.0f, 0.0f, 0.0f};   // column sums (per n)

#pragma unroll
  for (int m = 0; m < 4; ++m) {
#pragma unroll
    for (int i = 0; i < 4; ++i) {
      float rs = 0.0f;
#pragma unroll
      for (int n = 0; n < 4; ++n) {
        const float s = acc[m][n][i];
        const bool isdiag = diagWave && (m == n) && ((lr * 4 + i) == lc);
        float e = exp2f(s * RK10);
        if (isdiag) e = 0.0f;
        rs += e;
        cs[n] += e;
        if (unif) {
          float eu = exp2f(s * K4 - K4);
          if (isdiag) eu = 0.0f;
          u += eu;
        }
      }
      // row-sum: reduce over the 16 columns held by lanes sharing lr
      rs += __shfl_xor(rs, 1); rs += __shfl_xor(rs, 2);
      rs += __shfl_xor(rs, 4); rs += __shfl_xor(rs, 8);
      if (lc == 0) atomicAdd(&denom[row0 + wr * 64 + m * 16 + lr * 4 + i], rs);
    }
  }
  if (offdiag) {
    // column-sum: reduce over the 4 lr row-groups (lanes differing in bits 4,5)
#pragma unroll
    for (int n = 0; n < 4; ++n) {
      float c = cs[n];
      c += __shfl_xor(c, 16); c += __shfl_xor(c, 32);
      if (lr == 0) atomicAdd(&denom[col0 + wc * 64 + n * 16 + lc], c);
    }
  }
  if (unif) {
    for (int off = 1; off < 64; off <<= 1) u += __shfl_xor(u, off);
    if (lane == 0) red[w] = u;
    __syncthreads();
    if (tid == 0) {
      const float fac = offdiag ? 2.0f : 1.0f;   // mirror tile not computed
      atomicAdd(&scal[unif0 ? 2 : 3], fac * (red[0] + red[1] + red[2] + red[3]));
    }
  }
}

// ---------- kernel 3: sum of log(denom) ----------
__global__ __launch_bounds__(256) void klog(const float* __restrict__ denom,
                                            float* __restrict__ scal) {
  const int idx = blockIdx.x * 256 + threadIdx.x;
  const int lane = threadIdx.x & 63, w = threadIdx.x >> 6;
  __shared__ float red[4];
  float ld = logf(denom[idx]);
  for (int off = 1; off < 64; off <<= 1) ld += __shfl_xor(ld, off);
  if (lane == 0) red[w] = ld;
  __syncthreads();
  if (threadIdx.x == 0) atomicAdd(&scal[4], red[0] + red[1] + red[2] + red[3]);
}

// ---------- kernel 4: combine scalars ----------
__global__ void kfinal(const float* __restrict__ scal, float* __restrict__ out) {
  const float sum_pos = scal[0], sum_align = scal[1];
  const float U0 = scal[2], U1 = scal[3], sum_logd = scal[4];
  out[0] = (sum_logd - 20.0f * sum_pos) / 8192.0f;    // loss: (sum log d - 2*sum_pos/t)/2n
  out[1] = sum_align / 4096.0f;                        // lalign
  const float P = 2048.0f * 2047.0f * 0.5f;            // n_pairs per half
  out[2] = 0.5f * (logf(U0 * 0.5f / P) + logf(U1 * 0.5f / P));  // lunif
}

extern "C" void kernel_launch(void* const* d_in, const int* in_sizes, int n_in,
                              void* d_out, int out_size, void* d_ws, size_t ws_size,
                              hipStream_t stream) {
  const float* p1 = (const float*)d_in[0];
  const float* p2 = (const float*)d_in[1];
  float* out = (float*)d_out;
  char* ws = (char*)d_ws;
  unsigned short* z = (unsigned short*)ws;                    // 8192 x 1024 bf16 = 16 MB
  float* denom = (float*)(ws + (size_t)M_TOT * DDIM * 2);     // 8192 f32
  float* scal  = denom + M_TOT;                               // [pos, align, U0, U1, logd]

  hipMemsetAsync(denom, 0, (M_TOT + 8) * sizeof(float), stream);
  knorm<<<N_ROWS, 256, 0, stream>>>(p1, p2, z, scal);
  const int ntiles = 64 * 65 / 2;                             // lower triangle
  kgemm<<<ntiles, 256, 0, stream>>>(z, denom, scal);
  klog<<<M_TOT / 256, 256, 0, stream>>>(denom, scal);
  kfinal<<<1, 1, 0, stream>>>(scal, out);
}

// Round 3
// 229.132 us; speedup vs baseline: 1.5328x; 1.0921x over previous
//
#include <hip/hip_runtime.h>
#include <stdint.h>

#define DDIM   1024
#define M_TOT  8192
#define N_ROWS 4096
#define KT     16              // 1024 / BK=64
#define NBLK   1056            // sum over I of (2I+2), I=0..31 ; == 8*132
#define ASLOT  32768           // 256 rows x 64 k x 2B
#define BSLOT  16384           // 128 rows x 64 k x 2B
#define LDS_TOTAL (3*ASLOT + 3*BSLOT + 64)

typedef __attribute__((ext_vector_type(8))) short bf16x8;
typedef __attribute__((ext_vector_type(4))) float f32x4;

__device__ __forceinline__ unsigned short f2bf(float x) {
  union { float f; uint32_t u; } v; v.f = x;
  uint32_t r = v.u + 0x7FFFu + ((v.u >> 16) & 1u);
  return (unsigned short)(r >> 16);
}

__device__ __forceinline__ void gload_lds16(const void* g, void* l) {
  __builtin_amdgcn_global_load_lds(
      (const __attribute__((address_space(1))) uint32_t*)g,
      (__attribute__((address_space(3))) uint32_t*)l, 16, 0, 0);
}

// ---------- kernel 1: row-normalize both inputs, emit bf16 z, pos/align sums ----------
__global__ __launch_bounds__(256) void knorm(const float* __restrict__ p1,
                                             const float* __restrict__ p2,
                                             unsigned short* __restrict__ z,
                                             float* __restrict__ scal) {
  const int r = blockIdx.x;
  const int t = threadIdx.x;
  const int lane = t & 63, w = t >> 6;
  __shared__ float red0[4], red1[4];

  const float4 a = ((const float4*)(p1 + (size_t)r * DDIM))[t];
  const float4 b = ((const float4*)(p2 + (size_t)r * DDIM))[t];
  float s1 = a.x*a.x + a.y*a.y + a.z*a.z + a.w*a.w;
  float s2 = b.x*b.x + b.y*b.y + b.z*b.z + b.w*b.w;
  for (int off = 1; off < 64; off <<= 1) { s1 += __shfl_xor(s1, off); s2 += __shfl_xor(s2, off); }
  if (lane == 0) { red0[w] = s1; red1[w] = s2; }
  __syncthreads();
  const float S1 = red0[0] + red0[1] + red0[2] + red0[3];
  const float S2 = red1[0] + red1[1] + red1[2] + red1[3];
  const float r1 = 1.0f / sqrtf(S1);
  const float r2 = 1.0f / sqrtf(S2);
  const float n1x = a.x*r1, n1y = a.y*r1, n1z = a.z*r1, n1w = a.w*r1;
  const float n2x = b.x*r2, n2y = b.y*r2, n2z = b.z*r2, n2w = b.w*r2;
  float pos = n1x*n2x + n1y*n2y + n1z*n2z + n1w*n2w;
  float al  = (n1x-n2x)*(n1x-n2x) + (n1y-n2y)*(n1y-n2y)
            + (n1z-n2z)*(n1z-n2z) + (n1w-n2w)*(n1w-n2w);
  __syncthreads();
  for (int off = 1; off < 64; off <<= 1) { pos += __shfl_xor(pos, off); al += __shfl_xor(al, off); }
  if (lane == 0) { red0[w] = pos; red1[w] = al; }
  __syncthreads();
  if (t == 0) {
    atomicAdd(&scal[0], red0[0] + red0[1] + red0[2] + red0[3]);
    atomicAdd(&scal[1], red1[0] + red1[1] + red1[2] + red1[3]);
  }
  ushort4 o1, o2;
  o1.x = f2bf(n1x); o1.y = f2bf(n1y); o1.z = f2bf(n1z); o1.w = f2bf(n1w);
  o2.x = f2bf(n2x); o2.y = f2bf(n2y); o2.z = f2bf(n2z); o2.w = f2bf(n2w);
  ((ushort4*)(z + (size_t)r * DDIM))[t] = o1;
  ((ushort4*)(z + (size_t)(r + N_ROWS) * DDIM))[t] = o2;
}

// stage one 64-K-tile of A (256 rows) + B (128 rows) into LDS slot.
// Linear LDS dest (gload_lds requirement); source pre-swizzled with the
// same (row&7) chunk-XOR the ds_read applies (rule #21).
__device__ __forceinline__ void stage_tile(const char* zb, int rowA0, int colB0,
                                           int kt, char* As, char* Bs, int tid) {
  const int rsub = tid >> 3;                 // 0..63
  const int ch   = tid & 7;                  // 16B chunk in 128B row
  const int csrc = (ch ^ (rsub & 7)) << 4;   // row&7 == rsub&7 (q*64 ≡ 0 mod 8)
  const int kb   = kt * 128;
#pragma unroll
  for (int q = 0; q < 4; ++q) {
    const int row = q * 64 + rsub;
    gload_lds16(zb + (size_t)(rowA0 + row) * 2048 + kb + csrc, As + row * 128 + ch * 16);
  }
#pragma unroll
  for (int q = 0; q < 2; ++q) {
    const int row = q * 64 + rsub;
    gload_lds16(zb + (size_t)(colB0 + row) * 2048 + kb + csrc, Bs + row * 128 + ch * 16);
  }
}

// ---------- kernel 2: fused z@z^T, strict-lower-triangle coverage ----------
// BM=256 x BN=128 tiles, blocks (I,J) with J<=2I+1; universal element mask
// gcol<grow => every unordered pair computed exactly once. 3-slot LDS rotation,
// counted vmcnt(6) at group boundaries (T3+T4), raw s_barrier (no implicit drain).
__global__ __launch_bounds__(512) void kgemm(const unsigned short* __restrict__ z,
                                             float* __restrict__ denom,
                                             float* __restrict__ scal) {
  extern __shared__ char lds[];
  char* AsBase = lds;
  char* BsBase = lds + 3 * ASLOT;
  float* red = (float*)(lds + 3 * ASLOT + 3 * BSLOT);

  const int tid  = threadIdx.x;
  const int lane = tid & 63;
  const int wid  = tid >> 6;
  const int wsr  = wid >> 1, wsc = wid & 1;   // wave 64x64 sub-tile
  const int lr = lane >> 4, lc = lane & 15;

  // bijective XCD swizzle (1056 = 8*132), then triangle decode
  const int b = (blockIdx.x & 7) * 132 + (blockIdx.x >> 3);
  int I = (int)((sqrtf(4.0f * (float)b + 1.0f) - 1.0f) * 0.5f);
  while ((I + 1) * (I + 2) <= b) ++I;
  while (I * (I + 1) > b) --I;
  const int J = b - I * (I + 1);
  const int rowA0 = I * 256, colB0 = J * 128;

  const char* zb = (const char*)z;
  f32x4 acc[4][4] = {};

  // prologue: tiles 0,1 in flight; wait tile 0 resident (vmcnt 12->6)
  stage_tile(zb, rowA0, colB0, 0, AsBase, BsBase, tid);
  stage_tile(zb, rowA0, colB0, 1, AsBase + ASLOT, BsBase + BSLOT, tid);
  asm volatile("s_waitcnt vmcnt(6)" ::: "memory");
  __builtin_amdgcn_s_barrier();
  __builtin_amdgcn_sched_barrier(0);

  for (int t = 0; t < KT; ++t) {
    if (t + 2 < KT) {
      const int s2 = (t + 2) % 3;
      stage_tile(zb, rowA0, colB0, t + 2, AsBase + s2 * ASLOT, BsBase + s2 * BSLOT, tid);
    }
    __builtin_amdgcn_sched_barrier(0);
    const int s = t % 3;
    const char* At = AsBase + s * ASLOT;
    const char* Bt = BsBase + s * BSLOT;
    bf16x8 af[4][2], bg[4][2];
#pragma unroll
    for (int m = 0; m < 4; ++m) {
      const int r = wsr * 64 + m * 16 + lc;
      const int sw = (lc & 7) << 4;
#pragma unroll
      for (int kk = 0; kk < 2; ++kk)
        af[m][kk] = *(const bf16x8*)(At + r * 128 + ((kk * 64 + lr * 16) ^ sw));
    }
#pragma unroll
    for (int n = 0; n < 4; ++n) {
      const int r = wsc * 64 + n * 16 + lc;
      const int sw = (lc & 7) << 4;
#pragma unroll
      for (int kk = 0; kk < 2; ++kk)
        bg[n][kk] = *(const bf16x8*)(Bt + r * 128 + ((kk * 64 + lr * 16) ^ sw));
    }
    __builtin_amdgcn_s_setprio(1);
#pragma unroll
    for (int kk = 0; kk < 2; ++kk)
#pragma unroll
      for (int m = 0; m < 4; ++m)
#pragma unroll
        for (int n = 0; n < 4; ++n)
          acc[m][n] = __builtin_amdgcn_mfma_f32_16x16x32_bf16(af[m][kk], bg[n][kk], acc[m][n], 0, 0, 0);
    __builtin_amdgcn_s_setprio(0);
    // boundary: tile t+1 guaranteed resident (FIFO), tile t+2's 6 loads stay in flight
    if (t + 2 < KT) asm volatile("s_waitcnt vmcnt(6)" ::: "memory");
    else            asm volatile("s_waitcnt vmcnt(0)" ::: "memory");
    __builtin_amdgcn_s_barrier();
    __builtin_amdgcn_sched_barrier(0);
  }

  // ---- fused epilogue: strict-lower mask, row-sums + col-sums + unif ----
  const float RK10 = 14.426950408889634f;  // 10 * log2(e)
  const float K4   = 5.770780163555856f;   // 4 * log2(e)
  const bool unif = (I <= 7) || (I >= 8 && I <= 15 && J >= 16);
  const int  uidx = (I <= 7) ? 2 : 3;
  float u = 0.0f;
  float cs[4] = {0.0f, 0.0f, 0.0f, 0.0f};

#pragma unroll
  for (int m = 0; m < 4; ++m) {
    const int growb = rowA0 + wsr * 64 + m * 16 + lr * 4;
#pragma unroll
    for (int i = 0; i < 4; ++i) {
      const int grow = growb + i;
      float rs = 0.0f;
#pragma unroll
      for (int n = 0; n < 4; ++n) {
        const int gcol = colB0 + wsc * 64 + n * 16 + lc;
        const bool incl = (gcol < grow);
        float e = incl ? exp2f(acc[m][n][i] * RK10) : 0.0f;
        rs += e;
        cs[n] += e;
        if (unif) u += incl ? exp2f(acc[m][n][i] * K4 - K4) : 0.0f;
      }
      rs += __shfl_xor(rs, 1); rs += __shfl_xor(rs, 2);
      rs += __shfl_xor(rs, 4); rs += __shfl_xor(rs, 8);
      if (lc == 0) atomicAdd(&denom[grow], rs);
    }
  }
#pragma unroll
  for (int n = 0; n < 4; ++n) {
    float c = cs[n];
    c += __shfl_xor(c, 16); c += __shfl_xor(c, 32);
    if (lr == 0) atomicAdd(&denom[colB0 + wsc * 64 + n * 16 + lc], c);
  }
  if (unif) {
    for (int off = 1; off < 64; off <<= 1) u += __shfl_xor(u, off);
    if (lane == 0) red[wid] = u;
    __syncthreads();
    if (tid == 0) {
      float s8 = 0.0f;
#pragma unroll
      for (int i = 0; i < 8; ++i) s8 += red[i];
      atomicAdd(&scal[uidx], 2.0f * s8);   // each pair computed once; mirror via x2
    }
  }
}

// ---------- kernel 3: sum(log(denom)) + final combine (single block) ----------
__global__ __launch_bounds__(1024) void klogf(const float* __restrict__ denom,
                                              const float* __restrict__ scal,
                                              float* __restrict__ out) {
  __shared__ float red[16];
  const int tid = threadIdx.x;
  float s = 0.0f;
#pragma unroll
  for (int q = 0; q < 8; ++q) s += logf(denom[q * 1024 + tid]);
  const int lane = tid & 63, w = tid >> 6;
  for (int off = 1; off < 64; off <<= 1) s += __shfl_xor(s, off);
  if (lane == 0) red[w] = s;
  __syncthreads();
  if (tid == 0) {
    float S = 0.0f;
#pragma unroll
    for (int i = 0; i < 16; ++i) S += red[i];
    const float P = 2048.0f * 2047.0f * 0.5f;
    out[0] = (S - 20.0f * scal[0]) / 8192.0f;   // (sum log d - 2*sum_pos/t) / 2n
    out[1] = scal[1] / 4096.0f;                 // lalign
    out[2] = 0.5f * (logf(scal[2] * 0.5f / P) + logf(scal[3] * 0.5f / P));
  }
}

extern "C" void kernel_launch(void* const* d_in, const int* in_sizes, int n_in,
                              void* d_out, int out_size, void* d_ws, size_t ws_size,
                              hipStream_t stream) {
  const float* p1 = (const float*)d_in[0];
  const float* p2 = (const float*)d_in[1];
  float* out = (float*)d_out;
  char* ws = (char*)d_ws;
  unsigned short* z = (unsigned short*)ws;                    // 8192 x 1024 bf16 = 16 MB
  float* denom = (float*)(ws + (size_t)M_TOT * DDIM * 2);     // 8192 f32
  float* scal  = denom + M_TOT;                               // [pos, align, U0, U1]

  (void)hipFuncSetAttribute((const void*)kgemm,
                            hipFuncAttributeMaxDynamicSharedMemorySize, LDS_TOTAL);
  hipMemsetAsync(denom, 0, (M_TOT + 8) * sizeof(float), stream);
  knorm<<<N_ROWS, 256, 0, stream>>>(p1, p2, z, scal);
  kgemm<<<NBLK, 512, LDS_TOTAL, stream>>>(z, denom, scal);
  klogf<<<1, 1024, 0, stream>>>(denom, scal, out);
}